// Round 2
// baseline (1830.252 us; speedup 1.0000x reference)
//
#include <hip/hip_runtime.h>

#define T_ 4096
#define B_ 64
#define D_ 128
#define L_ 128

// ---------------------------------------------------------------------------
// Kernel 1: xp[t,b,:] = x[t,b,:] @ Wx + bx   (written into d_out, used as xp)
// 64 rows x 128 cols per WG, fp32 VALU GEMM. Wx staged in 32-k chunks so
// total LDS = 50.7 KB -> 3 blocks/CU.
// ---------------------------------------------------------------------------
__global__ __launch_bounds__(256, 3) void xp_gemm(
    const float* __restrict__ x, const float* __restrict__ Wx,
    const float* __restrict__ bx, float* __restrict__ xp)
{
  __shared__ float sX[64][132];   // 33.8 KB  (pad 132: rows spread banks)
  __shared__ float sW[32][132];   // 16.9 KB  (one 32-k chunk of Wx)
  const int j = threadIdx.x;
  const int m0 = blockIdx.x * 64;

  // Stage x tile (64x128) -> 2048 float4, 8 per thread.
#pragma unroll
  for (int r = 0; r < 8; ++r) {
    int f = r * 256 + j;
    int row = f >> 5, k4 = f & 31;
    float4 v = *reinterpret_cast<const float4*>(x + (size_t)(m0 + row) * 128 + k4 * 4);
    *reinterpret_cast<float4*>(&sX[row][k4 * 4]) = v;
  }
  // Stage Wx chunk 0 (k = 0..31).
#pragma unroll
  for (int r = 0; r < 4; ++r) {
    int f = r * 256 + j;
    int row = f >> 5, c4 = f & 31;
    float4 v = *reinterpret_cast<const float4*>(Wx + (size_t)row * 128 + c4 * 4);
    *reinterpret_cast<float4*>(&sW[row][c4 * 4]) = v;
  }
  __syncthreads();

  const int rr = j >> 4;          // 4 rows each
  const int cc = j & 15;
  const int c0 = cc * 4;          // col group A (cols 0..63)
  const int c1 = 64 + cc * 4;     // col group B (cols 64..127) -> 2-way LDS reads
  float a0[4][4], a1[4][4];
  float4 b0 = *reinterpret_cast<const float4*>(bx + c0);
  float4 b1 = *reinterpret_cast<const float4*>(bx + c1);
#pragma unroll
  for (int i2 = 0; i2 < 4; ++i2) {
    a0[i2][0] = b0.x; a0[i2][1] = b0.y; a0[i2][2] = b0.z; a0[i2][3] = b0.w;
    a1[i2][0] = b1.x; a1[i2][1] = b1.y; a1[i2][2] = b1.z; a1[i2][3] = b1.w;
  }

  for (int ch = 0; ch < 4; ++ch) {
#pragma unroll 2
    for (int k4 = 0; k4 < 8; ++k4) {
      float4 xv[4];
#pragma unroll
      for (int i2 = 0; i2 < 4; ++i2)
        xv[i2] = *reinterpret_cast<const float4*>(&sX[rr * 4 + i2][ch * 32 + k4 * 4]);
#pragma unroll
      for (int dk = 0; dk < 4; ++dk) {
        float4 w0 = *reinterpret_cast<const float4*>(&sW[k4 * 4 + dk][c0]);
        float4 w1 = *reinterpret_cast<const float4*>(&sW[k4 * 4 + dk][c1]);
#pragma unroll
        for (int i2 = 0; i2 < 4; ++i2) {
          float xs = (dk == 0) ? xv[i2].x : (dk == 1) ? xv[i2].y
                   : (dk == 2) ? xv[i2].z : xv[i2].w;
          a0[i2][0] = fmaf(xs, w0.x, a0[i2][0]);
          a0[i2][1] = fmaf(xs, w0.y, a0[i2][1]);
          a0[i2][2] = fmaf(xs, w0.z, a0[i2][2]);
          a0[i2][3] = fmaf(xs, w0.w, a0[i2][3]);
          a1[i2][0] = fmaf(xs, w1.x, a1[i2][0]);
          a1[i2][1] = fmaf(xs, w1.y, a1[i2][1]);
          a1[i2][2] = fmaf(xs, w1.z, a1[i2][2]);
          a1[i2][3] = fmaf(xs, w1.w, a1[i2][3]);
        }
      }
    }
    if (ch < 3) {
      __syncthreads();            // all reads of sW chunk done
#pragma unroll
      for (int r = 0; r < 4; ++r) {
        int f = r * 256 + j;
        int row = f >> 5, c4 = f & 31;
        float4 v = *reinterpret_cast<const float4*>(
            Wx + (size_t)((ch + 1) * 32 + row) * 128 + c4 * 4);
        *reinterpret_cast<float4*>(&sW[row][c4 * 4]) = v;
      }
      __syncthreads();            // chunk visible
    }
  }

#pragma unroll
  for (int i2 = 0; i2 < 4; ++i2) {
    float* p = xp + (size_t)(m0 + rr * 4 + i2) * 128;
    float4 o0 = {a0[i2][0], a0[i2][1], a0[i2][2], a0[i2][3]};
    float4 o1 = {a1[i2][0], a1[i2][1], a1[i2][2], a1[i2][3]};
    *reinterpret_cast<float4*>(p + c0) = o0;
    *reinterpret_cast<float4*>(p + c1) = o1;
  }
}

// ---------------------------------------------------------------------------
// Kernel 2: sequential scan, in place over io (= d_out holding xp).
// 64 WGs (one per batch / CU), 512 threads = 8 waves (2 per SIMD).
// Thread (w,i): l = w*16 + (i>>2), k-quarter kh = i&3 (32 k values each).
// Wh slice (32 fp32) in VGPRs; h double-buffered in LDS; raw s_barrier with
// lgkmcnt-only drain so global prefetch/store stay in flight across steps.
// ---------------------------------------------------------------------------
__global__ __launch_bounds__(512, 1) void rnn_scan(
    float* io, const float* __restrict__ h0,
    const float* __restrict__ Wh, const float* __restrict__ bh)
{
  __shared__ float hbuf[2][128];
  const int j = threadIdx.x;
  const int b = blockIdx.x;
  const int i = j & 63;
  const int l = ((j >> 6) << 4) | (i >> 2);   // output column, 0..127
  const int kh = i & 3;                        // k-quarter
  const int kb = kh << 5;                      // k base: 0,32,64,96

  // Wh[k][l] for this thread's k-quarter, loaded in ROTATED unit order so the
  // 4 k-quarters read disjoint LDS bank quads each step (conflict-free).
  float wh[32];
#pragma unroll
  for (int m = 0; m < 8; ++m) {
    int ku = (m + 2 * kh) & 7;                 // rotated b128 unit
#pragma unroll
    for (int e = 0; e < 4; ++e)
      wh[4 * m + e] = Wh[(size_t)(kb + ku * 4 + e) * 128 + l];
  }
  const float bhr = bh[l];

  if (j < 128) hbuf[0][j] = h0[(size_t)b * 128 + j];

  const size_t ss = (size_t)B_ * L_;           // 8192 floats per timestep
  const float* __restrict__ pf = io + (size_t)b * 128 + l;  // prefetch cursor
  float* outp = io + (size_t)b * 128 + l;      // H[t] store cursor

  // Prefetch queue, depth 8, statically indexed.
  float q[8];
#pragma unroll
  for (int u = 0; u < 8; ++u) q[u] = pf[u * ss];
  pf += 8 * ss;

  __syncthreads();

  for (int t8 = 0; t8 < T_ / 8; ++t8) {
#pragma unroll
    for (int u = 0; u < 8; ++u) {
      const int t = (t8 << 3) + u;
      const int pr = u & 1;                    // == t&1
      const float* hb = &hbuf[pr][kb];

      float c0 = 0.f, c1 = 0.f, c2 = 0.f, c3 = 0.f;
#pragma unroll
      for (int m = 0; m < 8; ++m) {
        int ku = (m + 2 * kh) & 7;
        float4 hv = *reinterpret_cast<const float4*>(hb + ku * 4);
        float acc = (m & 3) == 0 ? c0 : (m & 3) == 1 ? c1 : (m & 3) == 2 ? c2 : c3;
        acc = fmaf(hv.x, wh[4 * m + 0], acc);
        acc = fmaf(hv.y, wh[4 * m + 1], acc);
        acc = fmaf(hv.z, wh[4 * m + 2], acc);
        acc = fmaf(hv.w, wh[4 * m + 3], acc);
        if ((m & 3) == 0) c0 = acc; else if ((m & 3) == 1) c1 = acc;
        else if ((m & 3) == 2) c2 = acc; else c3 = acc;
      }
      float acc = (c0 + c1) + (c2 + c3);
      // butterfly over the 4 k-quarters (quad-perm DPP shuffles)
      acc += __shfl_xor(acc, 1, 64);
      acc += __shfl_xor(acc, 2, 64);
      float pre = acc + q[u] + bhr;

      // tanh(pre)
      float aa = fabsf(pre);
      float e2 = __expf(-2.f * aa);
      float r = (1.f - e2) * __builtin_amdgcn_rcpf(1.f + e2);
      float hn = copysignf(r, pre);

      if (kh == 0) hbuf[pr ^ 1][l] = hn;       // publish h_{t+1} (LDS)
      else if (kh == 3) outp[(size_t)t * ss] = hn;  // H[t] -> global (in flight)

      // prefetch xp[t+8] (clamped; clamped values never consumed)
      q[u] = (t + 8 < T_) ? pf[0] : 0.f;
      pf += ss;

      // LDS-only drain + raw barrier: global load/store stay in flight.
      asm volatile("s_waitcnt lgkmcnt(0)" ::: "memory");
      __builtin_amdgcn_s_barrier();
      __builtin_amdgcn_sched_barrier(0);
    }
  }
}

extern "C" void kernel_launch(void* const* d_in, const int* in_sizes, int n_in,
                              void* d_out, int out_size, void* d_ws, size_t ws_size,
                              hipStream_t stream) {
  const float* x  = (const float*)d_in[0];
  const float* h0 = (const float*)d_in[1];
  const float* Wx = (const float*)d_in[2];
  const float* bx = (const float*)d_in[3];
  const float* Wh = (const float*)d_in[4];
  const float* bh = (const float*)d_in[5];
  float* out = (float*)d_out;

  // Phase 1: xp = x @ Wx + bx, written into d_out.
  xp_gemm<<<(T_ * B_) / 64, 256, 0, stream>>>(x, Wx, bx, out);
  // Phase 2: in-place scan; H[t] overwrites xp[t] 8 steps after it is read.
  rnn_scan<<<B_, 512, 0, stream>>>(out, h0, Wh, bh);
}